// Round 1
// baseline (253.653 us; speedup 1.0000x reference)
//
#include <hip/hip_runtime.h>
#include <cstdint>
#include <cmath>

// Problem constants
#define B_    8
#define NHID_ 256
#define L_    2048
#define D_    512      // q/k/v channels (8 heads x 64)
#define DO_   2048     // output channels
#define QKVN  1536     // concat q|k|v

using u16    = unsigned short;
using short8 = __attribute__((ext_vector_type(8))) short;  // 8 bf16 (4 VGPRs)
using f32x4  = __attribute__((ext_vector_type(4))) float;  // 4 fp32 acc

typedef __attribute__((address_space(1))) void gv_t;
typedef __attribute__((address_space(3))) void lv_t;

__device__ inline void llds16(const void* g, void* l) {
  // async global->LDS, 16B/lane; LDS dest = wave-uniform base + lane*16
  __builtin_amdgcn_global_load_lds((const gv_t*)g, (lv_t*)l, 16, 0, 0);
}

__device__ inline u16 f32_to_bf16(float f) {
  unsigned u = __float_as_uint(f);
  u += 0x7fffu + ((u >> 16) & 1u);   // RNE (values finite)
  return (u16)(u >> 16);
}

__device__ inline void load8(const u16* p, float f[8]) {
  uint4 u = *reinterpret_cast<const uint4*>(p);
  f[0] = __uint_as_float(u.x << 16); f[1] = __uint_as_float(u.x & 0xffff0000u);
  f[2] = __uint_as_float(u.y << 16); f[3] = __uint_as_float(u.y & 0xffff0000u);
  f[4] = __uint_as_float(u.z << 16); f[5] = __uint_as_float(u.z & 0xffff0000u);
  f[6] = __uint_as_float(u.w << 16); f[7] = __uint_as_float(u.w & 0xffff0000u);
}

// ---------------------------------------------------------------------------
// prep: fp32 [rows][cols] -> bf16 [cols][rows] (transpose + convert)
// batch via blockIdx.z (stride rows*cols both sides). block (32,8).
// ---------------------------------------------------------------------------
__global__ void transpose_cvt(const float* __restrict__ src, u16* __restrict__ dst,
                              int rows, int cols) {
  __shared__ float tile[32][33];
  src += (size_t)blockIdx.z * rows * cols;
  dst += (size_t)blockIdx.z * rows * cols;
  int c0 = blockIdx.x * 32, r0 = blockIdx.y * 32;
  int tx = threadIdx.x, ty = threadIdx.y;
#pragma unroll
  for (int i = 0; i < 4; ++i)
    tile[ty + i * 8][tx] = src[(size_t)(r0 + ty + i * 8) * cols + c0 + tx];
  __syncthreads();
#pragma unroll
  for (int i = 0; i < 4; ++i)
    dst[(size_t)(c0 + ty + i * 8) * rows + r0 + tx] = f32_to_bf16(tile[tx][ty + i * 8]);
}

__global__ void concat_bias(const float* __restrict__ bq, const float* __restrict__ bk,
                            const float* __restrict__ bv, float* __restrict__ bqkv) {
  int d = blockIdx.x * 256 + threadIdx.x;
  float v = (d < 512) ? bq[d] : (d < 1024 ? bk[d - 512] : bv[d - 1024]);
  bqkv[d] = v;
}

// ---------------------------------------------------------------------------
// m97-style A*B^T GEMM core: A [M][K], B [N][K] bf16 row-major (K contiguous),
// 128x128 tile, BK=64, 256 threads = 4 waves (2x2), 4x4 16x16x32 MFMA per wave.
// K is compile-time; K == row stride of both operands.
// ---------------------------------------------------------------------------
#define BM 128
#define BN 128
#define BK 64

template <int K>
__device__ inline void gemm_tile(const u16* __restrict__ gA, const u16* __restrict__ gB,
                                 int m0, int n0, u16* As, u16* Bs, f32x4 (&acc)[4][4]) {
  const int tid = threadIdx.x;
  const int wave = tid >> 6, lane = tid & 63;
  const int wm = wave >> 1, wn = wave & 1;
  const int lrow = lane >> 3;          // 0..7  (staging row-in-chunk)
  const int lcol = (lane & 7) * 8;     // 0..56 (staging k offset)
  const int fr = lane & 15;            // fragment row/col
  const int fq = (lane >> 4) * 8;      // fragment k offset

#pragma unroll
  for (int i = 0; i < 4; ++i)
#pragma unroll
    for (int j = 0; j < 4; ++j) acc[i][j] = f32x4{0.f, 0.f, 0.f, 0.f};

  for (int k0 = 0; k0 < K; k0 += BK) {
#pragma unroll
    for (int t = 0; t < 4; ++t) {
      int chunk = wave * 4 + t;                 // 16 chunks of 1KB per tile
      int row = chunk * 8 + lrow;
      llds16(gA + (size_t)(m0 + row) * K + k0 + lcol, (char*)As + chunk * 1024);
      llds16(gB + (size_t)(n0 + row) * K + k0 + lcol, (char*)Bs + chunk * 1024);
    }
    __syncthreads();   // compiler emits s_waitcnt vmcnt(0) before s_barrier
#pragma unroll
    for (int ks = 0; ks < 2; ++ks) {
      short8 a[4], b[4];
#pragma unroll
      for (int mt = 0; mt < 4; ++mt)
        a[mt] = *(const short8*)(As + (wm * 64 + mt * 16 + fr) * BK + ks * 32 + fq);
#pragma unroll
      for (int nt = 0; nt < 4; ++nt)
        b[nt] = *(const short8*)(Bs + (wn * 64 + nt * 16 + fr) * BK + ks * 32 + fq);
#pragma unroll
      for (int mt = 0; mt < 4; ++mt)
#pragma unroll
        for (int nt = 0; nt < 4; ++nt)
          acc[mt][nt] = __builtin_amdgcn_mfma_f32_16x16x32_bf16(a[mt], b[nt], acc[mt][nt], 0, 0, 0);
    }
    __syncthreads();
  }
}

// QKV GEMM: C[bl][d] = xb[bl][c] * WqkvT[d][c] + bqkv[d], store bf16
__global__ __launch_bounds__(256) void qkv_gemm(const u16* __restrict__ xb,
                                                const u16* __restrict__ wT,
                                                const float* __restrict__ bqkv,
                                                u16* __restrict__ qkv) {
  __shared__ __align__(16) u16 As[BM * BK];
  __shared__ __align__(16) u16 Bs[BN * BK];
  int m0 = blockIdx.y * BM, n0 = blockIdx.x * BN;
  f32x4 acc[4][4];
  gemm_tile<NHID_>(xb, wT, m0, n0, As, Bs, acc);
  const int lane = threadIdx.x & 63, wave = threadIdx.x >> 6;
  const int wm = wave >> 1, wn = wave & 1;
#pragma unroll
  for (int mt = 0; mt < 4; ++mt) {
    int row0 = m0 + wm * 64 + mt * 16 + (lane >> 4) * 4;
#pragma unroll
    for (int nt = 0; nt < 4; ++nt) {
      int col = n0 + wn * 64 + nt * 16 + (lane & 15);
      float bias = bqkv[col];
#pragma unroll
      for (int r = 0; r < 4; ++r)
        qkv[(size_t)(row0 + r) * QKVN + col] = f32_to_bf16(acc[mt][nt][r] + bias);
    }
  }
}

// Out GEMM (swapped): C[j][l] = WoT[j][c] * att[b*L+l][c] + bo[j], fp32 store
// to out[b][j][l] -- coalesced along l (MFMA C col = lane&15).
__global__ __launch_bounds__(256) void out_gemm(const u16* __restrict__ woT,
                                                const u16* __restrict__ att,
                                                const float* __restrict__ bo,
                                                float* __restrict__ out) {
  __shared__ __align__(16) u16 As[BM * BK];
  __shared__ __align__(16) u16 Bs[BN * BK];
  int b = blockIdx.z;
  int m0 = blockIdx.y * BM;   // j
  int n0 = blockIdx.x * BN;   // l
  const u16* gB = att + (size_t)b * L_ * D_;
  f32x4 acc[4][4];
  gemm_tile<D_>(woT, gB, m0, n0, As, Bs, acc);
  const int lane = threadIdx.x & 63, wave = threadIdx.x >> 6;
  const int wm = wave >> 1, wn = wave & 1;
  float* outb = out + (size_t)b * DO_ * L_;
#pragma unroll
  for (int mt = 0; mt < 4; ++mt) {
    int row0 = m0 + wm * 64 + mt * 16 + (lane >> 4) * 4;
#pragma unroll
    for (int r = 0; r < 4; ++r) {
      float bias = bo[row0 + r];
#pragma unroll
      for (int nt = 0; nt < 4; ++nt) {
        int col = n0 + wn * 64 + nt * 16 + (lane & 15);
        outb[(size_t)(row0 + r) * L_ + col] = acc[mt][nt][r] + bias;
      }
    }
  }
}

// ---------------------------------------------------------------------------
// Windowed attention: one wave per (b,l). lane -> (head = lane>>3, 8 channels).
// OOB windows use k=v=0 and PARTICIPATE in softmax with score 0 (matches the
// reference's zero-padded extract_patches semantics).
// ---------------------------------------------------------------------------
__global__ __launch_bounds__(256) void attn_kernel(const u16* __restrict__ qkv,
                                                   u16* __restrict__ att) {
  const int wave = threadIdx.x >> 6, lane = threadIdx.x & 63;
  const int bl = blockIdx.x * 4 + wave;
  const int l = bl & (L_ - 1);
  const int c0 = (lane >> 3) * 64 + (lane & 7) * 8;   // channel base, 8 per lane

  float q[8];
  load8(qkv + (size_t)bl * QKVN + c0, q);

  float kk[3][8], vv[3][8];
#pragma unroll
  for (int w = 0; w < 3; ++w) {
    int lw = l + w - 1;
    if (lw >= 0 && lw < L_) {
      const u16* base = qkv + (size_t)(bl + w - 1) * QKVN;
      load8(base + 512 + c0, kk[w]);
      load8(base + 1024 + c0, vv[w]);
    } else {
#pragma unroll
      for (int t = 0; t < 8; ++t) { kk[w][t] = 0.f; vv[w][t] = 0.f; }
    }
  }

  float s[3];
#pragma unroll
  for (int w = 0; w < 3; ++w) {
    float a = 0.f;
#pragma unroll
    for (int t = 0; t < 8; ++t) a = fmaf(q[t], kk[w][t], a);
    s[w] = a;
  }
  // reduce over the 8 lanes of this head (butterfly; all lanes end with sum)
#pragma unroll
  for (int off = 1; off < 8; off <<= 1) {
    s[0] += __shfl_xor(s[0], off);
    s[1] += __shfl_xor(s[1], off);
    s[2] += __shfl_xor(s[2], off);
  }
  s[0] *= 0.125f; s[1] *= 0.125f; s[2] *= 0.125f;   // 1/sqrt(64)

  float mx = fmaxf(s[0], fmaxf(s[1], s[2]));
  float e0 = __expf(s[0] - mx), e1 = __expf(s[1] - mx), e2 = __expf(s[2] - mx);
  float inv = 1.f / (e0 + e1 + e2);
  float a0 = e0 * inv, a1 = e1 * inv, a2 = e2 * inv;

  u16 o16[8];
#pragma unroll
  for (int t = 0; t < 8; ++t) {
    float o = a0 * vv[0][t] + a1 * vv[1][t] + a2 * vv[2][t];
    o16[t] = f32_to_bf16(o);
  }
  uint4 pk;
  pk.x = (unsigned)o16[0] | ((unsigned)o16[1] << 16);
  pk.y = (unsigned)o16[2] | ((unsigned)o16[3] << 16);
  pk.z = (unsigned)o16[4] | ((unsigned)o16[5] << 16);
  pk.w = (unsigned)o16[6] | ((unsigned)o16[7] << 16);
  *reinterpret_cast<uint4*>(att + (size_t)bl * D_ + c0) = pk;
}

// ---------------------------------------------------------------------------
extern "C" void kernel_launch(void* const* d_in, const int* in_sizes, int n_in,
                              void* d_out, int out_size, void* d_ws, size_t ws_size,
                              hipStream_t stream) {
  const float* x  = (const float*)d_in[0];
  const float* Wq = (const float*)d_in[1];
  const float* bq = (const float*)d_in[2];
  const float* Wk = (const float*)d_in[3];
  const float* bk = (const float*)d_in[4];
  const float* Wv = (const float*)d_in[5];
  const float* bv = (const float*)d_in[6];
  const float* Wo = (const float*)d_in[7];
  const float* bo = (const float*)d_in[8];
  float* out = (float*)d_out;

  char* ws = (char*)d_ws;
  // workspace layout (bytes)
  u16*   xb    = (u16*)(ws + 0);            //  16384x256  bf16  (8388608)
  u16*   wqkvT = (u16*)(ws + 8388608);      //  1536x256   bf16  (786432)
  u16*   woT   = (u16*)(ws + 9175040);      //  2048x512   bf16  (2097152)
  float* bqkv  = (float*)(ws + 11272192);   //  1536       f32   (6144)
  u16*   qkv   = (u16*)(ws + 11278336);     //  16384x1536 bf16  (50331648)
  u16*   att   = (u16*)(ws + 61609984);     //  16384x512  bf16  (16777216)
  // total ~78.4 MB

  dim3 tb(32, 8);
  // x [B][256][2048] -> xb [(b*L+l)][c]
  transpose_cvt<<<dim3(L_ / 32, NHID_ / 32, B_), tb, 0, stream>>>(x, xb, NHID_, L_);
  // weights -> K-contiguous transposed bf16
  transpose_cvt<<<dim3(D_ / 32, NHID_ / 32, 1), tb, 0, stream>>>(Wq, wqkvT, NHID_, D_);
  transpose_cvt<<<dim3(D_ / 32, NHID_ / 32, 1), tb, 0, stream>>>(Wk, wqkvT + 512 * NHID_, NHID_, D_);
  transpose_cvt<<<dim3(D_ / 32, NHID_ / 32, 1), tb, 0, stream>>>(Wv, wqkvT + 1024 * NHID_, NHID_, D_);
  transpose_cvt<<<dim3(DO_ / 32, D_ / 32, 1), tb, 0, stream>>>(Wo, woT, D_, DO_);
  concat_bias<<<QKVN / 256, 256, 0, stream>>>(bq, bk, bv, bqkv);

  // QKV projection: [16384 x 1536] = xb [16384x256] * wqkvT^T
  qkv_gemm<<<dim3(QKVN / BN, (B_ * L_) / BM), 256, 0, stream>>>(xb, wqkvT, bqkv, qkv);

  // windowed softmax attention -> att [16384x512] bf16
  attn_kernel<<<(B_ * L_) / 4, 256, 0, stream>>>(qkv, att);

  // output projection, transposed store: out[b][j][l]
  out_gemm<<<dim3(L_ / BN, DO_ / BM, B_), 256, 0, stream>>>(woT, att, bo, out);
}

// Round 2
// 228.127 us; speedup vs baseline: 1.1119x; 1.1119x over previous
//
#include <hip/hip_runtime.h>
#include <cstdint>
#include <cmath>

// Problem constants
#define B_    8
#define NHID_ 256
#define L_    2048
#define D_    512      // q/k/v channels (8 heads x 64)
#define DO_   2048     // output channels
#define QKVN  1536     // concat q|k|v

using u16    = unsigned short;
using short8 = __attribute__((ext_vector_type(8))) short;  // 8 bf16 (4 VGPRs)
using f32x4  = __attribute__((ext_vector_type(4))) float;  // 4 fp32 acc

typedef __attribute__((address_space(1))) void gv_t;
typedef __attribute__((address_space(3))) void lv_t;

__device__ inline void llds16(const void* g, void* l) {
  // async global->LDS, 16B/lane; LDS dest = wave-uniform base + lane*16
  __builtin_amdgcn_global_load_lds((const gv_t*)g, (lv_t*)l, 16, 0, 0);
}

__device__ inline u16 f32_to_bf16(float f) {
  unsigned u = __float_as_uint(f);
  u += 0x7fffu + ((u >> 16) & 1u);   // RNE (values finite)
  return (u16)(u >> 16);
}

__device__ inline void load8(const u16* p, float f[8]) {
  uint4 u = *reinterpret_cast<const uint4*>(p);
  f[0] = __uint_as_float(u.x << 16); f[1] = __uint_as_float(u.x & 0xffff0000u);
  f[2] = __uint_as_float(u.y << 16); f[3] = __uint_as_float(u.y & 0xffff0000u);
  f[4] = __uint_as_float(u.z << 16); f[5] = __uint_as_float(u.z & 0xffff0000u);
  f[6] = __uint_as_float(u.w << 16); f[7] = __uint_as_float(u.w & 0xffff0000u);
}

// ---------------------------------------------------------------------------
// prep (single launch): fp32 [R][C] -> bf16 [C][R] transposes for x and all
// weights, plus bias concat. Flat grid, block-uniform branch per tile range.
// block (32,8).
// ---------------------------------------------------------------------------
template <int R, int C>
__device__ inline void t32(const float* __restrict__ src, u16* __restrict__ dst,
                           int id, float (*tile)[33]) {
  constexpr int TPR = C / 32;              // tiles along cols
  constexpr int PER = (R / 32) * TPR;      // tiles per z-slice
  int z = id / PER, rem = id % PER;
  int ry = rem / TPR, cx = rem % TPR;
  src += (size_t)z * R * C;
  dst += (size_t)z * R * C;
  int c0 = cx * 32, r0 = ry * 32;
  int tx = threadIdx.x, ty = threadIdx.y;
#pragma unroll
  for (int i = 0; i < 4; ++i)
    tile[ty + i * 8][tx] = src[(size_t)(r0 + ty + i * 8) * C + c0 + tx];
  __syncthreads();
#pragma unroll
  for (int i = 0; i < 4; ++i)
    dst[(size_t)(c0 + ty + i * 8) * R + r0 + tx] = f32_to_bf16(tile[tx][ty + i * 8]);
}

// block-id ranges
#define PREP_X0   0
#define PREP_WQ   4096     // x: 8 * (256/32) * (2048/32) = 4096 tiles
#define PREP_WK   4224     // Wq: (256/32)*(512/32) = 128 tiles
#define PREP_WV   4352
#define PREP_WO   4480
#define PREP_BIAS 5504     // Wo: (512/32)*(2048/32) = 1024 tiles
#define PREP_NB   5510     // bias: 1536/256 = 6 blocks

__global__ void prep_all(const float* __restrict__ x,
                         const float* __restrict__ Wq, const float* __restrict__ Wk,
                         const float* __restrict__ Wv, const float* __restrict__ Wo,
                         const float* __restrict__ bq, const float* __restrict__ bk,
                         const float* __restrict__ bv,
                         u16* __restrict__ xb, u16* __restrict__ wqkvT,
                         u16* __restrict__ woT, float* __restrict__ bqkv) {
  __shared__ float tile[32][33];
  int bid = blockIdx.x;
  if (bid < PREP_WQ) {
    t32<NHID_, L_>(x, xb, bid, tile);
  } else if (bid < PREP_WK) {
    t32<NHID_, D_>(Wq, wqkvT, bid - PREP_WQ, tile);
  } else if (bid < PREP_WV) {
    t32<NHID_, D_>(Wk, wqkvT + 512 * NHID_, bid - PREP_WK, tile);
  } else if (bid < PREP_WO) {
    t32<NHID_, D_>(Wv, wqkvT + 1024 * NHID_, bid - PREP_WV, tile);
  } else if (bid < PREP_BIAS) {
    t32<D_, DO_>(Wo, woT, bid - PREP_WO, tile);
  } else {
    int d = (bid - PREP_BIAS) * 256 + threadIdx.y * 32 + threadIdx.x;
    float v = (d < 512) ? bq[d] : (d < 1024 ? bk[d - 512] : bv[d - 1024]);
    bqkv[d] = v;
  }
}

// ---------------------------------------------------------------------------
// m97-style A*B^T GEMM core with XOR-swizzled LDS staging.
// A [M][K], B [N][K] bf16 row-major (K contiguous), 128x128 tile, BK=64,
// 256 threads = 4 waves (2x2), 4x4 16x16x32 MFMA per wave.
//
// Swizzle: global k-chunk c (8 elems = 16B) of tile-row r is staged at LDS
// slot c ^ (r&7). ds_read_b128 fragment reads then hit bank-quad
// ((fr&7)^C)*4 -> 8 distinct quads x 2 lanes = 2-way (free, m136) instead of
// the unswizzled 16-way conflict (row stride 128B == 32 banks).
// ---------------------------------------------------------------------------
#define BM 128
#define BN 128
#define BK 64

template <int K>
__device__ inline void gemm_tile(const u16* __restrict__ gA, const u16* __restrict__ gB,
                                 int m0, int n0, u16* As, u16* Bs, f32x4 (&acc)[4][4]) {
  const int tid = threadIdx.x;
  const int wave = tid >> 6, lane = tid & 63;
  const int wm = wave >> 1, wn = wave & 1;
  const int r8 = lane >> 3;                 // row within 8-row chunk
  const int kc = ((lane & 7) ^ r8) * 8;     // swizzled k element offset
  const int fr = lane & 15;                 // fragment row/col
  const int fx = fr & 7;                    // swizzle key for reads
  const int kq = lane >> 4;                 // fragment k-chunk 0..3

  auto stage = [&](int k0) {
#pragma unroll
    for (int t = 0; t < 4; ++t) {
      int chunk = wave * 4 + t;             // 16 chunks of 1KB per tile
      int row = chunk * 8 + r8;
      llds16(gA + (size_t)(m0 + row) * K + k0 + kc, (char*)As + chunk * 1024);
      llds16(gB + (size_t)(n0 + row) * K + k0 + kc, (char*)Bs + chunk * 1024);
    }
  };

  stage(0);                                 // overlap first staging with init
#pragma unroll
  for (int i = 0; i < 4; ++i)
#pragma unroll
    for (int j = 0; j < 4; ++j) acc[i][j] = f32x4{0.f, 0.f, 0.f, 0.f};

  for (int k0 = 0;;) {
    __syncthreads();                        // drains staging (vmcnt0 + barrier)
#pragma unroll
    for (int ks = 0; ks < 2; ++ks) {
      short8 a[4], b[4];
      const int slot = (((ks * 4 + kq) ^ fx)) * 8;
#pragma unroll
      for (int mt = 0; mt < 4; ++mt)
        a[mt] = *(const short8*)(As + (wm * 64 + mt * 16 + fr) * BK + slot);
#pragma unroll
      for (int nt = 0; nt < 4; ++nt)
        b[nt] = *(const short8*)(Bs + (wn * 64 + nt * 16 + fr) * BK + slot);
#pragma unroll
      for (int mt = 0; mt < 4; ++mt)
#pragma unroll
        for (int nt = 0; nt < 4; ++nt)
          acc[mt][nt] = __builtin_amdgcn_mfma_f32_16x16x32_bf16(a[mt], b[nt], acc[mt][nt], 0, 0, 0);
    }
    k0 += BK;
    if (k0 >= K) break;
    __syncthreads();                        // LDS reads done; safe to restage
    stage(k0);
  }
}

// QKV GEMM: C[bl][d] = xb[bl][c] * WqkvT[d][c] + bqkv[d], store bf16
__global__ __launch_bounds__(256) void qkv_gemm(const u16* __restrict__ xb,
                                                const u16* __restrict__ wT,
                                                const float* __restrict__ bqkv,
                                                u16* __restrict__ qkv) {
  __shared__ __align__(16) u16 As[BM * BK];
  __shared__ __align__(16) u16 Bs[BN * BK];
  int m0 = blockIdx.y * BM, n0 = blockIdx.x * BN;
  f32x4 acc[4][4];
  gemm_tile<NHID_>(xb, wT, m0, n0, As, Bs, acc);
  const int lane = threadIdx.x & 63, wave = threadIdx.x >> 6;
  const int wm = wave >> 1, wn = wave & 1;
#pragma unroll
  for (int mt = 0; mt < 4; ++mt) {
    int row0 = m0 + wm * 64 + mt * 16 + (lane >> 4) * 4;
#pragma unroll
    for (int nt = 0; nt < 4; ++nt) {
      int col = n0 + wn * 64 + nt * 16 + (lane & 15);
      float bias = bqkv[col];
#pragma unroll
      for (int r = 0; r < 4; ++r)
        qkv[(size_t)(row0 + r) * QKVN + col] = f32_to_bf16(acc[mt][nt][r] + bias);
    }
  }
}

// Out GEMM (swapped): C[j][l] = WoT[j][c] * att[b*L+l][c] + bo[j], fp32 store
// to out[b][j][l] -- coalesced along l (MFMA C col = lane&15).
__global__ __launch_bounds__(256) void out_gemm(const u16* __restrict__ woT,
                                                const u16* __restrict__ att,
                                                const float* __restrict__ bo,
                                                float* __restrict__ out) {
  __shared__ __align__(16) u16 As[BM * BK];
  __shared__ __align__(16) u16 Bs[BN * BK];
  int b = blockIdx.z;
  int m0 = blockIdx.y * BM;   // j
  int n0 = blockIdx.x * BN;   // l
  const u16* gB = att + (size_t)b * L_ * D_;
  f32x4 acc[4][4];
  gemm_tile<D_>(woT, gB, m0, n0, As, Bs, acc);
  const int lane = threadIdx.x & 63, wave = threadIdx.x >> 6;
  const int wm = wave >> 1, wn = wave & 1;
  float* outb = out + (size_t)b * DO_ * L_;
#pragma unroll
  for (int mt = 0; mt < 4; ++mt) {
    int row0 = m0 + wm * 64 + mt * 16 + (lane >> 4) * 4;
#pragma unroll
    for (int r = 0; r < 4; ++r) {
      float bias = bo[row0 + r];
#pragma unroll
      for (int nt = 0; nt < 4; ++nt) {
        int col = n0 + wn * 64 + nt * 16 + (lane & 15);
        outb[(size_t)(row0 + r) * L_ + col] = acc[mt][nt][r] + bias;
      }
    }
  }
}

// ---------------------------------------------------------------------------
// Windowed attention: one wave per (b,l). lane -> (head = lane>>3, 8 channels).
// OOB windows use k=v=0 and PARTICIPATE in softmax with score 0 (matches the
// reference's zero-padded extract_patches semantics).
// ---------------------------------------------------------------------------
__global__ __launch_bounds__(256) void attn_kernel(const u16* __restrict__ qkv,
                                                   u16* __restrict__ att) {
  const int wave = threadIdx.x >> 6, lane = threadIdx.x & 63;
  const int bl = blockIdx.x * 4 + wave;
  const int l = bl & (L_ - 1);
  const int c0 = (lane >> 3) * 64 + (lane & 7) * 8;   // channel base, 8 per lane

  float q[8];
  load8(qkv + (size_t)bl * QKVN + c0, q);

  float kk[3][8], vv[3][8];
#pragma unroll
  for (int w = 0; w < 3; ++w) {
    int lw = l + w - 1;
    if (lw >= 0 && lw < L_) {
      const u16* base = qkv + (size_t)(bl + w - 1) * QKVN;
      load8(base + 512 + c0, kk[w]);
      load8(base + 1024 + c0, vv[w]);
    } else {
#pragma unroll
      for (int t = 0; t < 8; ++t) { kk[w][t] = 0.f; vv[w][t] = 0.f; }
    }
  }

  float s[3];
#pragma unroll
  for (int w = 0; w < 3; ++w) {
    float a = 0.f;
#pragma unroll
    for (int t = 0; t < 8; ++t) a = fmaf(q[t], kk[w][t], a);
    s[w] = a;
  }
  // reduce over the 8 lanes of this head (butterfly; all lanes end with sum)
#pragma unroll
  for (int off = 1; off < 8; off <<= 1) {
    s[0] += __shfl_xor(s[0], off);
    s[1] += __shfl_xor(s[1], off);
    s[2] += __shfl_xor(s[2], off);
  }
  s[0] *= 0.125f; s[1] *= 0.125f; s[2] *= 0.125f;   // 1/sqrt(64)

  float mx = fmaxf(s[0], fmaxf(s[1], s[2]));
  float e0 = __expf(s[0] - mx), e1 = __expf(s[1] - mx), e2 = __expf(s[2] - mx);
  float inv = 1.f / (e0 + e1 + e2);
  float a0 = e0 * inv, a1 = e1 * inv, a2 = e2 * inv;

  u16 o16[8];
#pragma unroll
  for (int t = 0; t < 8; ++t) {
    float o = a0 * vv[0][t] + a1 * vv[1][t] + a2 * vv[2][t];
    o16[t] = f32_to_bf16(o);
  }
  uint4 pk;
  pk.x = (unsigned)o16[0] | ((unsigned)o16[1] << 16);
  pk.y = (unsigned)o16[2] | ((unsigned)o16[3] << 16);
  pk.z = (unsigned)o16[4] | ((unsigned)o16[5] << 16);
  pk.w = (unsigned)o16[6] | ((unsigned)o16[7] << 16);
  *reinterpret_cast<uint4*>(att + (size_t)bl * D_ + c0) = pk;
}

// ---------------------------------------------------------------------------
extern "C" void kernel_launch(void* const* d_in, const int* in_sizes, int n_in,
                              void* d_out, int out_size, void* d_ws, size_t ws_size,
                              hipStream_t stream) {
  const float* x  = (const float*)d_in[0];
  const float* Wq = (const float*)d_in[1];
  const float* bq = (const float*)d_in[2];
  const float* Wk = (const float*)d_in[3];
  const float* bk = (const float*)d_in[4];
  const float* Wv = (const float*)d_in[5];
  const float* bv = (const float*)d_in[6];
  const float* Wo = (const float*)d_in[7];
  const float* bo = (const float*)d_in[8];
  float* out = (float*)d_out;

  char* ws = (char*)d_ws;
  // workspace layout (bytes)
  u16*   xb    = (u16*)(ws + 0);            //  16384x256  bf16  (8388608)
  u16*   wqkvT = (u16*)(ws + 8388608);      //  1536x256   bf16  (786432)
  u16*   woT   = (u16*)(ws + 9175040);      //  2048x512   bf16  (2097152)
  float* bqkv  = (float*)(ws + 11272192);   //  1536       f32   (6144)
  u16*   qkv   = (u16*)(ws + 11278336);     //  16384x1536 bf16  (50331648)
  u16*   att   = (u16*)(ws + 61609984);     //  16384x512  bf16  (16777216)
  // total ~78.4 MB

  // all transposes + bias in ONE launch
  prep_all<<<PREP_NB, dim3(32, 8), 0, stream>>>(x, Wq, Wk, Wv, Wo, bq, bk, bv,
                                                xb, wqkvT, woT, bqkv);

  // QKV projection: [16384 x 1536] = xb [16384x256] * wqkvT^T
  qkv_gemm<<<dim3(QKVN / BN, (B_ * L_) / BM), 256, 0, stream>>>(xb, wqkvT, bqkv, qkv);

  // windowed softmax attention -> att [16384x512] bf16
  attn_kernel<<<(B_ * L_) / 4, 256, 0, stream>>>(qkv, att);

  // output projection, transposed store: out[b][j][l]
  out_gemm<<<dim3(L_ / BN, DO_ / BM, B_), 256, 0, stream>>>(woT, att, bo, out);
}